// Round 6
// baseline (740.242 us; speedup 1.0000x reference)
//
#include <hip/hip_runtime.h>
#include <math.h>

#define NB 65536
#define DIM 256

// Staged-W geometry (fp16, padded-linear k-rows).
// ROWB = 264 halves = 528 B = 33*16B: ds_read_b128-aligned, start banks spread
// uniformly across lanes (8 lanes per 16B slot = structural minimum).
// Stage tile = 2 experts x 32 cols = 33792 B; 16 tiles per layer
// (8 nt x 2 expert-pairs). Double-buffered: 67584 B + sC + sBias = 72 KB/block
// -> 2 blocks/CU (16 waves/CU, 4 waves/SIMD).
#define ROWB   528              // bytes per k-row (K=256 halves + 8 pad halves)
#define ESEC   16896            // bytes per expert section: 32 cols * 528
#define TILEB  33792            // bytes per stage tile: 2 experts * ESEC
#define LAYB   540672           // bytes per layer in W16 image: 16 tiles

typedef _Float16 half8  __attribute__((ext_vector_type(8)));   // 4 VGPRs
typedef _Float16 half2v __attribute__((ext_vector_type(2)));
typedef float    f32x4  __attribute__((ext_vector_type(4)));

// ---- W pre-pass: fp32 [e][k][n] -> fp16 staged image [L][tile][el][col][k] ----
// tile = nt*2 + (e>>1); el = e&1; col = n&31.
__global__ __launch_bounds__(256) void convert_w(
    const float* __restrict__ W1, const float* __restrict__ W2,
    const float* __restrict__ W3, char* __restrict__ W16T)
{
  const int g  = blockIdx.x * 256 + threadIdx.x;
  const int n  = g & 255;          // global output column
  const int k8 = (g >> 8) & 31;    // 16-byte k chunk (8 halves)
  const int e  = (g >> 13) & 3;
  const int L  = g >> 15;
  const float* WL  = (L == 0) ? W1 : (L == 1) ? W2 : W3;
  const float* src = WL + (size_t)e * DIM * DIM + (size_t)k8 * 8 * DIM + n;
  half8 h;
  #pragma unroll
  for (int j = 0; j < 8; ++j) h[j] = (_Float16)src[(size_t)j * DIM];
  const int s = (n >> 5) * 2 + (e >> 1);   // tile index 0..15
  *(half8*)(W16T + (size_t)L * LAYB + (size_t)s * TILEB
            + (e & 1) * ESEC + (n & 31) * ROWB + k8 * 16) = h;
}

// One cyclic-MoE layer: Out[b,:] = act( sum_e C[b,e]*(X[b,:] @ W_e + bias_e) )
// R6: spill-free 16 waves/CU. R5 post-mortem: 1024-thread block made the
// allocator cap VGPR at 64 -> afr spilled to scratch (FETCH 425MB, 175us).
// But occupancy 43% + HBM 3.5 TB/s were PROVEN schedulable. This round keeps
// R2's proven 108-VGPR per-wave structure (m_rep=2, afr[2][8], creg) and gets
// 16 waves/CU via 2 co-resident 512-thread blocks (grid=512, LDS 72KB/block).
//   - 16 phases = 8 nt x 2 expert-pairs; tile s lives in buffer s&1 (STATIC
//     buffer + creg indices -> no runtime-indexed register arrays).
//   - counted barriers: epilogue-half vmcnt(8), other half vmcnt(0).
template<bool WF16, bool IN_F16, bool OUT_F16, bool RELU>
__global__ __launch_bounds__(512, 4) void moe_layer(
    const void* __restrict__ Xin_,
    const float* __restrict__ phi,
    const float* __restrict__ Wf32,   // [4,256,256] fp32 (fallback path only)
    const char* __restrict__ W16,     // this layer's staged fp16 image (LAYB bytes)
    const float* __restrict__ bias,   // [4,256] fp32
    void* __restrict__ Out_,
    float acc_scale, float store_scale)
{
  __shared__ __attribute__((aligned(16))) char sStage[2][TILEB];  // 2 x 33 KB
  __shared__ float sC[128][4];       // per-row expert coefficients
  __shared__ float sBias[4][DIM];

  const int tid  = threadIdx.x;
  const int row0 = blockIdx.x * 128;
  const int wave = tid >> 6;
  const int lane = tid & 63;
  const int quad = lane >> 4;
  const int l15  = lane & 15;
  const int ms   = wave & 3;         // row group: 32 rows (0..3)
  const int cs   = wave >> 2;        // col half: 16 cols (0..1)

  // --- staging helper: one 33792 B tile, 512 threads ---
  // 4 full 8192 B sweeps (tid*16) + 1024 B remainder (wave 0, lane*16).
  // LDS dest linear (base + lane*16) as global_load_lds requires.
  auto stage = [&](char* l_base, int s) {
    if constexpr (WF16) {
      const char* g_ = W16 + (size_t)s * TILEB + tid * 16;
      char*       l_ = l_base + tid * 16;
      #pragma unroll
      for (int j = 0; j < 4; ++j)
        __builtin_amdgcn_global_load_lds(
            (const __attribute__((address_space(1))) unsigned int*)(g_ + j * 8192),
            (__attribute__((address_space(3))) unsigned int*)(l_ + j * 8192),
            16, 0, 0);
      if (wave == 0)   // last 1024 B (wave-uniform branch)
        __builtin_amdgcn_global_load_lds(
            (const __attribute__((address_space(1))) unsigned int*)(g_ + 32768),
            (__attribute__((address_space(3))) unsigned int*)(l_ + 32768),
            16, 0, 0);
    } else {
      // fp32 fallback: tile s = experts {2*(s&1)... } cols (s>>1)*32..+32.
      const int nt = s >> 1, ep = s & 1;
      #pragma unroll
      for (int it = 0; it < 4; ++it) {
        const int p  = it * 512 + tid;   // 2048 (el, k-pair, n4) units
        const int el = p >> 10;
        const int k2 = (p & 1023) >> 3;  // 0..127
        const int ng = p & 7;            // n-group of 4 cols
        const float* Wp = Wf32 + (size_t)(ep * 2 + el) * DIM * DIM
                        + (size_t)(k2 * 2) * DIM + nt * 32 + ng * 4;
        const float4 v0 = *(const float4*)Wp;
        const float4 v1 = *(const float4*)(Wp + DIM);
        const float s0[4] = {v0.x, v0.y, v0.z, v0.w};
        const float s1[4] = {v1.x, v1.y, v1.z, v1.w};
        #pragma unroll
        for (int j = 0; j < 4; ++j) {
          half2v h;
          h[0] = (_Float16)s0[j];
          h[1] = (_Float16)s1[j];
          *(half2v*)(l_base + el * ESEC + (ng * 4 + j) * ROWB + k2 * 4) = h;
        }
      }
    }
  };

  // --- prologue: kick off first stage, coefficients, bias, A-fragments ---
  stage(&sStage[0][0], 0);

  if (tid < 128) {
    const float w  = phi[row0 + tid] * (float)(2.0 / M_PI);  // [0,4]
    const int   wi = (int)w;                                 // trunc toward zero
    const float w2 = w * w, w3 = w2 * w;
    const float cf[4] = {
      -0.5f * w + w2 - 0.5f * w3,
      -2.5f * w2 + 1.5f * w3,
       0.5f * w + 2.0f * w2 - 1.5f * w3,
      -0.5f * w2 + 0.5f * w3 };
    #pragma unroll
    for (int e = 0; e < 4; ++e) sC[tid][e] = cf[(e + 1 - wi) & 3];
  }
  #pragma unroll
  for (int i = tid; i < 4 * DIM; i += 512) sBias[i >> 8][i & 255] = bias[i];

  // A fragments (fp16): wave owns 32 rows = 2 m-tiles x 8 k-chunks (64 VGPR).
  half8 afr[2][8];
  #pragma unroll
  for (int m = 0; m < 2; ++m) {
    const size_t row = (size_t)(row0 + ms * 32 + m * 16 + l15);
    if constexpr (IN_F16) {
      const _Float16* xr = (const _Float16*)Xin_ + row * DIM;
      #pragma unroll
      for (int kb = 0; kb < 8; ++kb)
        afr[m][kb] = *(const half8*)(xr + kb * 32 + quad * 8);
    } else {
      const float* xr = (const float*)Xin_ + row * DIM;
      #pragma unroll
      for (int kb = 0; kb < 8; ++kb) {
        const float4 a = *(const float4*)(xr + kb * 32 + quad * 8);
        const float4 b = *(const float4*)(xr + kb * 32 + quad * 8 + 4);
        half8 h;
        h[0] = (_Float16)a.x; h[1] = (_Float16)a.y;
        h[2] = (_Float16)a.z; h[3] = (_Float16)a.w;
        h[4] = (_Float16)b.x; h[5] = (_Float16)b.y;
        h[6] = (_Float16)b.z; h[7] = (_Float16)b.w;
        afr[m][kb] = h;
      }
    }
  }

  __syncthreads();   // full drain: stage(0) + sC + sBias ready; vmcnt clean slate

  // Per-row mixing coefficients in registers (hardcoded C/D mapping,
  // probe-proven prior session: row = quad*4 + reg, col = lane&15).
  float creg[2][4][4];
  #pragma unroll
  for (int m = 0; m < 2; ++m)
    #pragma unroll
    for (int r = 0; r < 4; ++r) {
      const int rl = ms * 32 + m * 16 + quad * 4 + r;
      #pragma unroll
      for (int e = 0; e < 4; ++e) creg[m][r][e] = sC[rl][e];
    }

  // --- main loop: 8 nt iterations x 2 phases; tile s lives in buffer s&1 ---
  for (int nt = 0; nt < 8; ++nt) {
    const int s = nt * 2;
    float fin[2][4];
    #pragma unroll
    for (int m = 0; m < 2; ++m)
      #pragma unroll
      for (int r = 0; r < 4; ++r) fin[m][r] = 0.f;

    // ===== first half: compute tile s (buffer 0, experts 0,1); prefetch s+1 =====
    stage(&sStage[1][0], s + 1);
    {
      const char* sb = &sStage[0][0];
      __builtin_amdgcn_s_setprio(1);
      #pragma unroll
      for (int el = 0; el < 2; ++el) {
        f32x4 acc[2];
        acc[0] = (f32x4){0.f, 0.f, 0.f, 0.f};
        acc[1] = (f32x4){0.f, 0.f, 0.f, 0.f};
        #pragma unroll
        for (int kb = 0; kb < 8; ++kb) {
          const half8 b = *(const half8*)(sb + el * ESEC + (cs * 16 + l15) * ROWB
                                          + kb * 64 + quad * 16);
          acc[0] = __builtin_amdgcn_mfma_f32_16x16x32_f16(afr[0][kb], b, acc[0], 0, 0, 0);
          acc[1] = __builtin_amdgcn_mfma_f32_16x16x32_f16(afr[1][kb], b, acc[1], 0, 0, 0);
        }
        #pragma unroll
        for (int m = 0; m < 2; ++m)
          #pragma unroll
          for (int r = 0; r < 4; ++r)
            fin[m][r] += creg[m][r][el] * acc[m][r];       // e = el (static)
      }
      __builtin_amdgcn_s_setprio(0);
    }
    if constexpr (WF16) {
      __builtin_amdgcn_sched_barrier(0);
      asm volatile("s_waitcnt vmcnt(0)" ::: "memory");     // buffer-1 prefetch done
      __builtin_amdgcn_s_barrier();
      __builtin_amdgcn_sched_barrier(0);
    } else {
      __syncthreads();
    }

    // ===== second half: compute tile s+1 (buffer 1, experts 2,3); prefetch s+2 =====
    if (nt < 7) stage(&sStage[0][0], s + 2);
    {
      const char* sb = &sStage[1][0];
      __builtin_amdgcn_s_setprio(1);
      #pragma unroll
      for (int el = 0; el < 2; ++el) {
        f32x4 acc[2];
        acc[0] = (f32x4){0.f, 0.f, 0.f, 0.f};
        acc[1] = (f32x4){0.f, 0.f, 0.f, 0.f};
        #pragma unroll
        for (int kb = 0; kb < 8; ++kb) {
          const half8 b = *(const half8*)(sb + el * ESEC + (cs * 16 + l15) * ROWB
                                          + kb * 64 + quad * 16);
          acc[0] = __builtin_amdgcn_mfma_f32_16x16x32_f16(afr[0][kb], b, acc[0], 0, 0, 0);
          acc[1] = __builtin_amdgcn_mfma_f32_16x16x32_f16(afr[1][kb], b, acc[1], 0, 0, 0);
        }
        #pragma unroll
        for (int m = 0; m < 2; ++m)
          #pragma unroll
          for (int r = 0; r < 4; ++r)
            fin[m][r] += creg[m][r][2 + el] * acc[m][r];   // e = 2+el (static)
      }
      __builtin_amdgcn_s_setprio(0);
    }

    // --- epilogue for nt: 8 stores, issued AFTER this half's prefetch ---
    {
      const int n_l = nt * 32 + cs * 16 + l15;   // col = lane&15
      float be[4];
      #pragma unroll
      for (int e = 0; e < 4; ++e) be[e] = sBias[e][n_l];
      #pragma unroll
      for (int m = 0; m < 2; ++m)
        #pragma unroll
        for (int r = 0; r < 4; ++r) {
          const int row_l = ms * 32 + m * 16 + quad * 4 + r;   // row = quad*4+reg
          float v = acc_scale * fin[m][r];
          #pragma unroll
          for (int e = 0; e < 4; ++e) v += creg[m][r][e] * be[e];
          if (RELU) v = fmaxf(v, 0.f);
          v *= store_scale;
          const size_t idx = (size_t)(row0 + row_l) * DIM + n_l;
          if (OUT_F16) ((_Float16*)Out_)[idx] = (_Float16)v;
          else         ((float*)Out_)[idx] = v;
        }
    }

    if constexpr (WF16) {
      // Counted barrier (T4): the 8 epilogue stores are the newest VMEM ops;
      // vmcnt(8) leaves them in flight while guaranteeing the (older) buffer-0
      // prefetch has landed for the next nt iteration.
      __builtin_amdgcn_sched_barrier(0);
      asm volatile("s_waitcnt vmcnt(8)" ::: "memory");
      __builtin_amdgcn_s_barrier();
      __builtin_amdgcn_sched_barrier(0);
    } else {
      __syncthreads();
    }
  }
}

extern "C" void kernel_launch(void* const* d_in, const int* in_sizes, int n_in,
                              void* d_out, int out_size, void* d_ws, size_t ws_size,
                              hipStream_t stream) {
  const float* X   = (const float*)d_in[0];
  const float* phi = (const float*)d_in[1];
  const float* W1  = (const float*)d_in[2];
  const float* b1  = (const float*)d_in[3];
  const float* W2  = (const float*)d_in[4];
  const float* b2  = (const float*)d_in[5];
  const float* W3  = (const float*)d_in[6];
  const float* b3  = (const float*)d_in[7];

  // Buffer plan (proven):
  //   H1 fp16 (32 MB) -> lower half of d_out.
  //   H2 fp16 (32 MB) -> d_ws if it fits, else dead X buffer (restored by harness).
  //   W16 image (~1.6 MB) -> d_ws tail when room; else fp32 staging path.
  //   H2 stored pre-scaled by 1/8; layer 3 undoes (x8).
  const size_t h2_bytes  = (size_t)NB * DIM * sizeof(_Float16);
  const size_t w16_bytes = (size_t)3 * LAYB;

  _Float16* H1  = (_Float16*)d_out;
  _Float16* H2;
  char*     W16 = nullptr;
  if (ws_size >= h2_bytes + w16_bytes) {
    H2  = (_Float16*)d_ws;
    W16 = (char*)d_ws + h2_bytes;
  } else if (ws_size >= h2_bytes) {
    H2 = (_Float16*)d_ws;                 // no W16 room -> fp32 staging
  } else if (ws_size >= w16_bytes) {
    W16 = (char*)d_ws;
    H2  = (_Float16*)d_in[0];
  } else {
    H2 = (_Float16*)d_in[0];
  }
  float* out = (float*)d_out;

  dim3 grid(NB / 128);    // 512 blocks = 2 per CU
  dim3 block(512);

  if (W16) {
    convert_w<<<dim3(384), dim3(256), 0, stream>>>(W1, W2, W3, W16);
    moe_layer<true, false, true,  true ><<<grid, block, 0, stream>>>(X,  phi, nullptr, W16,            b1, H1,  1.0f, 1.0f);
    moe_layer<true, true,  true,  true ><<<grid, block, 0, stream>>>(H1, phi, nullptr, W16 + LAYB,     b2, H2,  1.0f, 0.125f);
    moe_layer<true, true,  false, false><<<grid, block, 0, stream>>>(H2, phi, nullptr, W16 + 2 * LAYB, b3, out, 8.0f, 1.0f);
  } else {
    moe_layer<false, false, true,  true ><<<grid, block, 0, stream>>>(X,  phi, W1, nullptr, b1, H1,  1.0f, 1.0f);
    moe_layer<false, true,  true,  true ><<<grid, block, 0, stream>>>(H1, phi, W2, nullptr, b2, H2,  1.0f, 0.125f);
    moe_layer<false, true,  false, false><<<grid, block, 0, stream>>>(H2, phi, W3, nullptr, b3, out, 8.0f, 1.0f);
  }
}

// Round 7
// 262.495 us; speedup vs baseline: 2.8200x; 2.8200x over previous
//
#include <hip/hip_runtime.h>
#include <math.h>

#define NB 65536
#define DIM 256

// Staged-W geometry (fp16, padded-linear k-rows).
// ROWB = 264 halves = 528 B = 33*16B: ds_read_b128-aligned, start banks spread
// uniformly across lanes (8 lanes per 16B slot = structural minimum).
// Stage tile = 2 experts x 32 cols = 33792 B; 16 tiles per layer
// (8 nt x 2 expert-pairs). Double-buffered: 67584 B + sC + sBias = 72 KB/block
// -> 2 blocks/CU (16 waves/CU, 4 waves/SIMD).
#define ROWB   528              // bytes per k-row (K=256 halves + 8 pad halves)
#define ESEC   16896            // bytes per expert section: 32 cols * 528
#define TILEB  33792            // bytes per stage tile: 2 experts * ESEC
#define LAYB   540672           // bytes per layer in W16 image: 16 tiles

typedef _Float16 half8  __attribute__((ext_vector_type(8)));   // 4 VGPRs
typedef _Float16 half2v __attribute__((ext_vector_type(2)));
typedef float    f32x4  __attribute__((ext_vector_type(4)));

// ---- W pre-pass: fp32 [e][k][n] -> fp16 staged image [L][tile][el][col][k] ----
// tile = nt*2 + (e>>1); el = e&1; col = n&31.
__global__ __launch_bounds__(256) void convert_w(
    const float* __restrict__ W1, const float* __restrict__ W2,
    const float* __restrict__ W3, char* __restrict__ W16T)
{
  const int g  = blockIdx.x * 256 + threadIdx.x;
  const int n  = g & 255;          // global output column
  const int k8 = (g >> 8) & 31;    // 16-byte k chunk (8 halves)
  const int e  = (g >> 13) & 3;
  const int L  = g >> 15;
  const float* WL  = (L == 0) ? W1 : (L == 1) ? W2 : W3;
  const float* src = WL + (size_t)e * DIM * DIM + (size_t)k8 * 8 * DIM + n;
  half8 h;
  #pragma unroll
  for (int j = 0; j < 8; ++j) h[j] = (_Float16)src[(size_t)j * DIM];
  const int s = (n >> 5) * 2 + (e >> 1);   // tile index 0..15
  *(half8*)(W16T + (size_t)L * LAYB + (size_t)s * TILEB
            + (e & 1) * ESEC + (n & 31) * ROWB + k8 * 16) = h;
}

// One cyclic-MoE layer: Out[b,:] = act( sum_e C[b,e]*(X[b,:] @ W_e + bias_e) )
// R7: the ONE change vs R6 is __launch_bounds__(512, 2).
// R5/R6 post-mortem decoded the toolchain's launch_bounds semantics
// empirically: (256,2)->108 VGPR, (512,2)->128, (1024,4)->64, (512,4)->64 —
// i.e. arg behaves as min-BLOCKS/CU (waves/CU = arg*block_waves, capped 32;
// VGPR cap = 512/(waves per SIMD)). (512,4) therefore capped VGPR at 64,
// spilling afr[2][8] (64 VGPRs alone) -> FETCH 676MB scratch thrash.
// (512,2) caps at 128: our logical set (afr 64 + creg 32 + fin/acc/temps)
// compiled to 108 under the same structure in R2 -> spill-free.
// Occupancy: LDS 72KB/block -> 2 blocks/CU = 16 waves/CU = 4 waves/SIMD,
// exactly what 128-VGPR waves fit. This realizes the spill-free 16-wave
// config whose schedulability R5/R6 proved (occ ~40%) but poisoned w/ spills.
template<bool WF16, bool IN_F16, bool OUT_F16, bool RELU>
__global__ __launch_bounds__(512, 2) void moe_layer(
    const void* __restrict__ Xin_,
    const float* __restrict__ phi,
    const float* __restrict__ Wf32,   // [4,256,256] fp32 (fallback path only)
    const char* __restrict__ W16,     // this layer's staged fp16 image (LAYB bytes)
    const float* __restrict__ bias,   // [4,256] fp32
    void* __restrict__ Out_,
    float acc_scale, float store_scale)
{
  __shared__ __attribute__((aligned(16))) char sStage[2][TILEB];  // 2 x 33 KB
  __shared__ float sC[128][4];       // per-row expert coefficients
  __shared__ float sBias[4][DIM];

  const int tid  = threadIdx.x;
  const int row0 = blockIdx.x * 128;
  const int wave = tid >> 6;
  const int lane = tid & 63;
  const int quad = lane >> 4;
  const int l15  = lane & 15;
  const int ms   = wave & 3;         // row group: 32 rows (0..3)
  const int cs   = wave >> 2;        // col half: 16 cols (0..1)

  // --- staging helper: one 33792 B tile, 512 threads ---
  // 4 full 8192 B sweeps (tid*16) + 1024 B remainder (wave 0, lane*16).
  // LDS dest linear (base + lane*16) as global_load_lds requires.
  auto stage = [&](char* l_base, int s) {
    if constexpr (WF16) {
      const char* g_ = W16 + (size_t)s * TILEB + tid * 16;
      char*       l_ = l_base + tid * 16;
      #pragma unroll
      for (int j = 0; j < 4; ++j)
        __builtin_amdgcn_global_load_lds(
            (const __attribute__((address_space(1))) unsigned int*)(g_ + j * 8192),
            (__attribute__((address_space(3))) unsigned int*)(l_ + j * 8192),
            16, 0, 0);
      if (wave == 0)   // last 1024 B (wave-uniform branch)
        __builtin_amdgcn_global_load_lds(
            (const __attribute__((address_space(1))) unsigned int*)(g_ + 32768),
            (__attribute__((address_space(3))) unsigned int*)(l_ + 32768),
            16, 0, 0);
    } else {
      // fp32 fallback: tile s = experts {2*(s&1)...} cols (s>>1)*32..+32.
      const int nt = s >> 1, ep = s & 1;
      #pragma unroll
      for (int it = 0; it < 4; ++it) {
        const int p  = it * 512 + tid;   // 2048 (el, k-pair, n4) units
        const int el = p >> 10;
        const int k2 = (p & 1023) >> 3;  // 0..127
        const int ng = p & 7;            // n-group of 4 cols
        const float* Wp = Wf32 + (size_t)(ep * 2 + el) * DIM * DIM
                        + (size_t)(k2 * 2) * DIM + nt * 32 + ng * 4;
        const float4 v0 = *(const float4*)Wp;
        const float4 v1 = *(const float4*)(Wp + DIM);
        const float s0[4] = {v0.x, v0.y, v0.z, v0.w};
        const float s1[4] = {v1.x, v1.y, v1.z, v1.w};
        #pragma unroll
        for (int j = 0; j < 4; ++j) {
          half2v h;
          h[0] = (_Float16)s0[j];
          h[1] = (_Float16)s1[j];
          *(half2v*)(l_base + el * ESEC + (ng * 4 + j) * ROWB + k2 * 4) = h;
        }
      }
    }
  };

  // --- prologue: kick off first stage, coefficients, bias, A-fragments ---
  stage(&sStage[0][0], 0);

  if (tid < 128) {
    const float w  = phi[row0 + tid] * (float)(2.0 / M_PI);  // [0,4]
    const int   wi = (int)w;                                 // trunc toward zero
    const float w2 = w * w, w3 = w2 * w;
    const float cf[4] = {
      -0.5f * w + w2 - 0.5f * w3,
      -2.5f * w2 + 1.5f * w3,
       0.5f * w + 2.0f * w2 - 1.5f * w3,
      -0.5f * w2 + 0.5f * w3 };
    #pragma unroll
    for (int e = 0; e < 4; ++e) sC[tid][e] = cf[(e + 1 - wi) & 3];
  }
  #pragma unroll
  for (int i = tid; i < 4 * DIM; i += 512) sBias[i >> 8][i & 255] = bias[i];

  // A fragments (fp16): wave owns 32 rows = 2 m-tiles x 8 k-chunks (64 VGPR).
  half8 afr[2][8];
  #pragma unroll
  for (int m = 0; m < 2; ++m) {
    const size_t row = (size_t)(row0 + ms * 32 + m * 16 + l15);
    if constexpr (IN_F16) {
      const _Float16* xr = (const _Float16*)Xin_ + row * DIM;
      #pragma unroll
      for (int kb = 0; kb < 8; ++kb)
        afr[m][kb] = *(const half8*)(xr + kb * 32 + quad * 8);
    } else {
      const float* xr = (const float*)Xin_ + row * DIM;
      #pragma unroll
      for (int kb = 0; kb < 8; ++kb) {
        const float4 a = *(const float4*)(xr + kb * 32 + quad * 8);
        const float4 b = *(const float4*)(xr + kb * 32 + quad * 8 + 4);
        half8 h;
        h[0] = (_Float16)a.x; h[1] = (_Float16)a.y;
        h[2] = (_Float16)a.z; h[3] = (_Float16)a.w;
        h[4] = (_Float16)b.x; h[5] = (_Float16)b.y;
        h[6] = (_Float16)b.z; h[7] = (_Float16)b.w;
        afr[m][kb] = h;
      }
    }
  }

  __syncthreads();   // full drain: stage(0) + sC + sBias ready; vmcnt clean slate

  // Per-row mixing coefficients in registers (hardcoded C/D mapping,
  // probe-proven prior session: row = quad*4 + reg, col = lane&15).
  float creg[2][4][4];
  #pragma unroll
  for (int m = 0; m < 2; ++m)
    #pragma unroll
    for (int r = 0; r < 4; ++r) {
      const int rl = ms * 32 + m * 16 + quad * 4 + r;
      #pragma unroll
      for (int e = 0; e < 4; ++e) creg[m][r][e] = sC[rl][e];
    }

  // --- main loop: 8 nt iterations x 2 phases; tile s lives in buffer s&1 ---
  for (int nt = 0; nt < 8; ++nt) {
    const int s = nt * 2;
    float fin[2][4];
    #pragma unroll
    for (int m = 0; m < 2; ++m)
      #pragma unroll
      for (int r = 0; r < 4; ++r) fin[m][r] = 0.f;

    // ===== first half: compute tile s (buffer 0, experts 0,1); prefetch s+1 =====
    stage(&sStage[1][0], s + 1);
    {
      const char* sb = &sStage[0][0];
      __builtin_amdgcn_s_setprio(1);
      #pragma unroll
      for (int el = 0; el < 2; ++el) {
        f32x4 acc[2];
        acc[0] = (f32x4){0.f, 0.f, 0.f, 0.f};
        acc[1] = (f32x4){0.f, 0.f, 0.f, 0.f};
        #pragma unroll
        for (int kb = 0; kb < 8; ++kb) {
          const half8 b = *(const half8*)(sb + el * ESEC + (cs * 16 + l15) * ROWB
                                          + kb * 64 + quad * 16);
          acc[0] = __builtin_amdgcn_mfma_f32_16x16x32_f16(afr[0][kb], b, acc[0], 0, 0, 0);
          acc[1] = __builtin_amdgcn_mfma_f32_16x16x32_f16(afr[1][kb], b, acc[1], 0, 0, 0);
        }
        #pragma unroll
        for (int m = 0; m < 2; ++m)
          #pragma unroll
          for (int r = 0; r < 4; ++r)
            fin[m][r] += creg[m][r][el] * acc[m][r];       // e = el (static)
      }
      __builtin_amdgcn_s_setprio(0);
    }
    if constexpr (WF16) {
      __builtin_amdgcn_sched_barrier(0);
      asm volatile("s_waitcnt vmcnt(0)" ::: "memory");     // buffer-1 prefetch done
      __builtin_amdgcn_s_barrier();
      __builtin_amdgcn_sched_barrier(0);
    } else {
      __syncthreads();
    }

    // ===== second half: compute tile s+1 (buffer 1, experts 2,3); prefetch s+2 =====
    if (nt < 7) stage(&sStage[0][0], s + 2);
    {
      const char* sb = &sStage[1][0];
      __builtin_amdgcn_s_setprio(1);
      #pragma unroll
      for (int el = 0; el < 2; ++el) {
        f32x4 acc[2];
        acc[0] = (f32x4){0.f, 0.f, 0.f, 0.f};
        acc[1] = (f32x4){0.f, 0.f, 0.f, 0.f};
        #pragma unroll
        for (int kb = 0; kb < 8; ++kb) {
          const half8 b = *(const half8*)(sb + el * ESEC + (cs * 16 + l15) * ROWB
                                          + kb * 64 + quad * 16);
          acc[0] = __builtin_amdgcn_mfma_f32_16x16x32_f16(afr[0][kb], b, acc[0], 0, 0, 0);
          acc[1] = __builtin_amdgcn_mfma_f32_16x16x32_f16(afr[1][kb], b, acc[1], 0, 0, 0);
        }
        #pragma unroll
        for (int m = 0; m < 2; ++m)
          #pragma unroll
          for (int r = 0; r < 4; ++r)
            fin[m][r] += creg[m][r][2 + el] * acc[m][r];   // e = 2+el (static)
      }
      __builtin_amdgcn_s_setprio(0);
    }

    // --- epilogue for nt: 8 stores, issued AFTER this half's prefetch ---
    {
      const int n_l = nt * 32 + cs * 16 + l15;   // col = lane&15
      float be[4];
      #pragma unroll
      for (int e = 0; e < 4; ++e) be[e] = sBias[e][n_l];
      #pragma unroll
      for (int m = 0; m < 2; ++m)
        #pragma unroll
        for (int r = 0; r < 4; ++r) {
          const int row_l = ms * 32 + m * 16 + quad * 4 + r;   // row = quad*4+reg
          float v = acc_scale * fin[m][r];
          #pragma unroll
          for (int e = 0; e < 4; ++e) v += creg[m][r][e] * be[e];
          if (RELU) v = fmaxf(v, 0.f);
          v *= store_scale;
          const size_t idx = (size_t)(row0 + row_l) * DIM + n_l;
          if (OUT_F16) ((_Float16*)Out_)[idx] = (_Float16)v;
          else         ((float*)Out_)[idx] = v;
        }
    }

    if constexpr (WF16) {
      // Counted barrier (T4): the 8 epilogue stores are the newest VMEM ops;
      // vmcnt(8) leaves them in flight while guaranteeing the (older) buffer-0
      // prefetch has landed for the next nt iteration.
      __builtin_amdgcn_sched_barrier(0);
      asm volatile("s_waitcnt vmcnt(8)" ::: "memory");
      __builtin_amdgcn_s_barrier();
      __builtin_amdgcn_sched_barrier(0);
    } else {
      __syncthreads();
    }
  }
}

extern "C" void kernel_launch(void* const* d_in, const int* in_sizes, int n_in,
                              void* d_out, int out_size, void* d_ws, size_t ws_size,
                              hipStream_t stream) {
  const float* X   = (const float*)d_in[0];
  const float* phi = (const float*)d_in[1];
  const float* W1  = (const float*)d_in[2];
  const float* b1  = (const float*)d_in[3];
  const float* W2  = (const float*)d_in[4];
  const float* b2  = (const float*)d_in[5];
  const float* W3  = (const float*)d_in[6];
  const float* b3  = (const float*)d_in[7];

  // Buffer plan (proven):
  //   H1 fp16 (32 MB) -> lower half of d_out.
  //   H2 fp16 (32 MB) -> d_ws if it fits, else dead X buffer (restored by harness).
  //   W16 image (~1.6 MB) -> d_ws tail when room; else fp32 staging path.
  //   H2 stored pre-scaled by 1/8; layer 3 undoes (x8).
  const size_t h2_bytes  = (size_t)NB * DIM * sizeof(_Float16);
  const size_t w16_bytes = (size_t)3 * LAYB;

  _Float16* H1  = (_Float16*)d_out;
  _Float16* H2;
  char*     W16 = nullptr;
  if (ws_size >= h2_bytes + w16_bytes) {
    H2  = (_Float16*)d_ws;
    W16 = (char*)d_ws + h2_bytes;
  } else if (ws_size >= h2_bytes) {
    H2 = (_Float16*)d_ws;                 // no W16 room -> fp32 staging
  } else if (ws_size >= w16_bytes) {
    W16 = (char*)d_ws;
    H2  = (_Float16*)d_in[0];
  } else {
    H2 = (_Float16*)d_in[0];
  }
  float* out = (float*)d_out;

  dim3 grid(NB / 128);    // 512 blocks = 2 per CU
  dim3 block(512);

  if (W16) {
    convert_w<<<dim3(384), dim3(256), 0, stream>>>(W1, W2, W3, W16);
    moe_layer<true, false, true,  true ><<<grid, block, 0, stream>>>(X,  phi, nullptr, W16,            b1, H1,  1.0f, 1.0f);
    moe_layer<true, true,  true,  true ><<<grid, block, 0, stream>>>(H1, phi, nullptr, W16 + LAYB,     b2, H2,  1.0f, 0.125f);
    moe_layer<true, true,  false, false><<<grid, block, 0, stream>>>(H2, phi, nullptr, W16 + 2 * LAYB, b3, out, 8.0f, 1.0f);
  } else {
    moe_layer<false, false, true,  true ><<<grid, block, 0, stream>>>(X,  phi, W1, nullptr, b1, H1,  1.0f, 1.0f);
    moe_layer<false, true,  true,  true ><<<grid, block, 0, stream>>>(H1, phi, W2, nullptr, b2, H2,  1.0f, 0.125f);
    moe_layer<false, true,  false, false><<<grid, block, 0, stream>>>(H2, phi, W3, nullptr, b3, out, 8.0f, 1.0f);
  }
}